// Round 4
// baseline (180.239 us; speedup 1.0000x reference)
//
#include <hip/hip_runtime.h>
#include <cstdint>
#include <cstddef>

// Problem constants (match reference)
#define Bc 2
#define Mc 2048
#define Rc 256
#define Hc 16
#define DHc 64
#define Dc (Hc * DHc)
#define NKT (Mc / 64)      // 32 key tiles total
#define NSPLIT 2
#define NKT2 (NKT / NSPLIT)

typedef __attribute__((ext_vector_type(8))) short short8;     // 8 bf16 (4 VGPRs)
typedef __attribute__((ext_vector_type(4))) float float4v;    // MFMA C/D frag
typedef __attribute__((ext_vector_type(4))) unsigned short ushort4v;
typedef __attribute__((ext_vector_type(8))) unsigned short ushort8v;
typedef __attribute__((ext_vector_type(4))) unsigned int uint4v;

// exp path: native exp2 (v_exp_f32); 0.125*log2(e) folded into Q at proj
#if __has_builtin(__builtin_amdgcn_exp2f)
#define EXPFN(x) __builtin_amdgcn_exp2f(x)
#define QSCALE 0.18033688f       // 0.125 * log2(e)
#define MADD_KEEP (-28.8539008f) // -20 * log2(e)
#else
#define EXPFN(x) __expf(x)
#define QSCALE 0.125f
#define MADD_KEEP (-20.0f)
#endif

// round-to-nearest-even f32 -> bf16
__device__ inline unsigned short f2bf(float f) {
    union { float f; uint32_t u; } v;
    v.f = f;
    uint32_t r = v.u + 0x7fffu + ((v.u >> 16) & 1u);
    return (unsigned short)(r >> 16);
}

// XOR-swizzled byte offset for [row][8 x 16B-chunk] LDS tiles (row = 128 B).
__device__ inline int swz(int row, int chunk) {
    return row * 128 + ((chunk ^ (row & 7)) << 4);
}

// ---------------------------------------------------------------------------
// Proj: one kernel, all three x = P@V + b (+RoPE / +transpose), everything
// inlined (fp32->bf16 conversion and B-transpose in staging, RoPE in epilogue).
// grid (M/128=16, D/128=8, 3 mats * B=6) = 768 blocks, block 256 (4 waves).
// 128x128 tile, K=256 in 4 chunks of 64; XOR-swizzled LDS.
// Wave w owns quadrant (mh=w&1 rows, dh2=w>>1 cols) = 4x4 MFMA tiles.
// mat 0 (Q): RoPE + QSCALE -> [bh][m][dh]; mat 1 (K): RoPE -> same layout;
// mat 2 (V): out transposed [bh][dh][m].
// ---------------------------------------------------------------------------
__global__ __launch_bounds__(256)
void proj_kernel(const float* __restrict__ Pq, const float* __restrict__ Pk,
                 const float* __restrict__ Pv,
                 const float* __restrict__ Vq, const float* __restrict__ Vk,
                 const float* __restrict__ Vv,
                 const float* __restrict__ bq, const float* __restrict__ bk,
                 const float* __restrict__ bv,
                 const int* __restrict__ pos_ids,
                 unsigned short* __restrict__ Qb, unsigned short* __restrict__ Kb,
                 unsigned short* __restrict__ Vta)
{
    __shared__ __align__(16) unsigned char AtB[128 * 128];  // A[m][64k] bf16 swizzled
    __shared__ __align__(16) unsigned char BtB[128 * 128];  // B[d][64k] bf16 swizzled

    const int tid = threadIdx.x;
    const int z = blockIdx.z, mat = z >> 1, b = z & 1;
    const int m0 = blockIdx.x * 128, d0 = blockIdx.y * 128;
    const int w = tid >> 6, lane = tid & 63, col = lane & 15, quad = lane >> 4;
    const int mh = w & 1, dh2 = w >> 1;

    const float* P  = mat == 0 ? Pq : (mat == 1 ? Pk : Pv);
    const float* Vm = mat == 0 ? Vq : (mat == 1 ? Vk : Vv);
    const float* Pg = P + ((size_t)b * Mc + m0) * Rc;

    // A staging: thread covers row arow, 32 consecutive floats (4 bf16 chunks)
    const int arow = tid >> 1, ac0 = (tid & 1) * 4;     // chunk base (8 shorts each)
    // B staging: thread covers k-row bkr, 32 consecutive d (transposed scatter)
    const int bkr = tid >> 2, bd = (tid & 3) * 32;

    float4v acc[4][4] = {};   // [mt][dt]

    for (int kc = 0; kc < 4; ++kc) {
        // issue global loads for this chunk before the barrier
        float4 af[8], bf4[8];
        #pragma unroll
        for (int i = 0; i < 8; ++i)
            af[i] = *(const float4*)&Pg[(size_t)arow * Rc + kc * 64 + (tid & 1) * 32 + i * 4];
        #pragma unroll
        for (int i = 0; i < 8; ++i)
            bf4[i] = *(const float4*)&Vm[(size_t)(kc * 64 + bkr) * Dc + d0 + bd + i * 4];
        // convert A early to shrink live set across the barrier
        ushort8v ua[4];
        #pragma unroll
        for (int i = 0; i < 4; ++i) {
            float4 f0 = af[2 * i], f1 = af[2 * i + 1];
            ushort8v u = { f2bf(f0.x), f2bf(f0.y), f2bf(f0.z), f2bf(f0.w),
                           f2bf(f1.x), f2bf(f1.y), f2bf(f1.z), f2bf(f1.w) };
            ua[i] = u;
        }
        __syncthreads();   // previous chunk's readers done
        #pragma unroll
        for (int i = 0; i < 4; ++i)
            *(ushort8v*)(AtB + swz(arow, ac0 + i)) = ua[i];
        // B transpose scatter: Bt[d][k] = Vm[k][d0+d], scalar b16 writes
        #pragma unroll
        for (int i = 0; i < 8; ++i) {
            const float* fp = (const float*)&bf4[i];
            #pragma unroll
            for (int c = 0; c < 4; ++c) {
                int d = bd + i * 4 + c;
                *(unsigned short*)(BtB + d * 128 + (((bkr >> 3) ^ (d & 7)) << 4)
                                   + (bkr & 7) * 2) = f2bf(fp[c]);
            }
        }
        __syncthreads();

        #pragma unroll
        for (int kk = 0; kk < 2; ++kk) {
            short8 afr[4], bfr[4];
            #pragma unroll
            for (int mt = 0; mt < 4; ++mt)
                afr[mt] = *(const short8*)(AtB + swz(mh * 64 + mt * 16 + col, kk * 4 + quad));
            #pragma unroll
            for (int dt = 0; dt < 4; ++dt)
                bfr[dt] = *(const short8*)(BtB + swz(dh2 * 64 + dt * 16 + col, kk * 4 + quad));
            #pragma unroll
            for (int mt = 0; mt < 4; ++mt)
                #pragma unroll
                for (int dt = 0; dt < 4; ++dt)
                    acc[mt][dt] = __builtin_amdgcn_mfma_f32_16x16x32_bf16(
                        afr[mt], bfr[dt], acc[mt][dt], 0, 0, 0);
        }
    }

    const int head = (d0 + dh2 * 64) >> 6;   // each wave's 64 cols = one head
    const int bh = b * Hc + head;

    if (mat < 2) {
        // RoPE inline: pairs (j, j+32) live in dt chunks (0,2) and (1,3)
        const float* bias = mat == 0 ? bq : bk;
        unsigned short* outp = mat == 0 ? Qb : Kb;
        const float oscale = mat == 0 ? QSCALE : 1.0f;
        float b00 = bias[head * 64 + col],      b01 = bias[head * 64 + 16 + col];
        float b10 = bias[head * 64 + 32 + col], b11 = bias[head * 64 + 48 + col];
        // inv_freq for j=col and j=col+16: 10000^(-j/32)
        float if0 = __expf(-0.28782314f * (float)col);
        float if1 = __expf(-0.28782314f * (float)(col + 16));
        #pragma unroll
        for (int mt = 0; mt < 4; ++mt)
            #pragma unroll
            for (int r = 0; r < 4; ++r) {
                int m = m0 + mh * 64 + mt * 16 + quad * 4 + r;
                float pos = (float)pos_ids[b * Mc + m];
                float a0 = pos * if0, a1 = pos * if1;
                float cs0 = __cosf(a0), sn0 = __sinf(a0);
                float cs1 = __cosf(a1), sn1 = __sinf(a1);
                float x00 = acc[mt][0][r] + b00, x10 = acc[mt][2][r] + b10;
                float x01 = acc[mt][1][r] + b01, x11 = acc[mt][3][r] + b11;
                unsigned short* og = outp + ((size_t)bh * Mc + m) * DHc;
                og[col]      = f2bf((x00 * cs0 - x10 * sn0) * oscale);
                og[32 + col] = f2bf((x00 * sn0 + x10 * cs0) * oscale);
                og[16 + col] = f2bf((x01 * cs1 - x11 * sn1) * oscale);
                og[48 + col] = f2bf((x01 * sn1 + x11 * cs1) * oscale);
            }
    } else {
        // V: store transposed [bh][dh][m], 4 consecutive m per b64 store
        #pragma unroll
        for (int dt = 0; dt < 4; ++dt) {
            int d = d0 + dh2 * 64 + dt * 16 + col;
            float bb = bv[d];
            int dh = d & 63;
            #pragma unroll
            for (int mt = 0; mt < 4; ++mt) {
                ushort4v pv;
                #pragma unroll
                for (int r = 0; r < 4; ++r) pv[r] = f2bf(acc[mt][dt][r] + bb);
                size_t base = ((size_t)bh * DHc + dh) * Mc + m0 + mh * 64 + mt * 16 + quad * 4;
                *(ushort4v*)&Vta[base] = pv;
            }
        }
    }
}

// ---------------------------------------------------------------------------
// Attn: flash attention, split-K by 2 for occupancy.
// grid (M/128=16, B*H=32, 2 splits) = 1024 blocks, block 256 (4 waves).
// Each block handles 128 queries x 1024 keys (16 tiles of 64); writes
// UNNORMALIZED O (fp32) + per-row l; combine kernel finishes.
// S^T MFMA (K as A, Q-regs as B): lane owns q = qs*16+(lane&15); no in-loop
// shuffles; p = exp2(s' + madd), mask folded into madd via int4 loads.
// ---------------------------------------------------------------------------
__global__ __launch_bounds__(256, 2)
void attn_kernel(const unsigned short* __restrict__ Qb,
                 const unsigned short* __restrict__ Kb,
                 const unsigned short* __restrict__ Vt,
                 const int* __restrict__ mask,   // [B][M]
                 float* __restrict__ O0,         // split 0 -> d_out (unnormalized)
                 float* __restrict__ O1,         // split 1 -> ws
                 float* __restrict__ lpart)      // [2][B*H][M]
{
    __shared__ __align__(16) unsigned char KsB[64 * 128];     // [key][dh] swizzled
    __shared__ __align__(16) unsigned char VsB[64 * 128];     // [dh][key] swizzled
    __shared__ __align__(16) unsigned short Ps[4][32][72];    // per-wave P [q][key]

    const int tid = threadIdx.x;
    const int q0 = blockIdx.x * 128;
    const int bh = blockIdx.y;
    const int b  = bh >> 4;
    const int s  = blockIdx.z;
    const int w = tid >> 6, lane = tid & 63, col = lane & 15, quad = lane >> 4;

    // Q frags (B-operand), loop-invariant: q = q0 + w*32 + qs*16 + col
    short8 qf[2][2];
    #pragma unroll
    for (int qs = 0; qs < 2; ++qs) {
        const unsigned short* Qg =
            Qb + ((size_t)bh * Mc + q0 + w * 32 + qs * 16 + col) * DHc + quad * 8;
        qf[qs][0] = *(const short8*)Qg;
        qf[qs][1] = *(const short8*)(Qg + 32);
    }

    // staging: thread covers 16B chunks (row=tid>>3, c=tid&7) and row+32
    const int srow = tid >> 3, sc = tid & 7;
    const int dst0 = swz(srow, sc), dst1 = swz(srow + 32, sc);
    // split s covers keys [s*1024, s*1024+1024)
    const unsigned short* Kg = Kb + (size_t)bh * Mc * DHc + (size_t)s * (Mc / 2) * DHc;
    const unsigned short* Vg = Vt + (size_t)bh * DHc * Mc + s * (Mc / 2);
    const int* mp = mask + b * Mc + s * (Mc / 2);

    uint4v kr0 = *(const uint4v*)&Kg[(size_t)srow * DHc + sc * 8];
    uint4v kr1 = *(const uint4v*)&Kg[(size_t)(srow + 32) * DHc + sc * 8];
    uint4v vr0 = *(const uint4v*)&Vg[(size_t)srow * Mc + sc * 8];
    uint4v vr1 = *(const uint4v*)&Vg[(size_t)(srow + 32) * Mc + sc * 8];

    float lsum[2] = {0.0f, 0.0f};
    float4v acc_o[2][4] = {};    // [qs][ds]

    for (int kt = 0; kt < NKT2; ++kt) {
        __syncthreads();
        *(uint4v*)(KsB + dst0) = kr0; *(uint4v*)(KsB + dst1) = kr1;
        *(uint4v*)(VsB + dst0) = vr0; *(uint4v*)(VsB + dst1) = vr1;
        __syncthreads();

        if (kt + 1 < NKT2) {   // prefetch next tile into registers
            const unsigned short* Kn = Kg + (size_t)(kt + 1) * 64 * DHc;
            kr0 = *(const uint4v*)&Kn[(size_t)srow * DHc + sc * 8];
            kr1 = *(const uint4v*)&Kn[(size_t)(srow + 32) * DHc + sc * 8];
            vr0 = *(const uint4v*)&Vg[(size_t)srow * Mc + (kt + 1) * 64 + sc * 8];
            vr1 = *(const uint4v*)&Vg[(size_t)(srow + 32) * Mc + (kt + 1) * 64 + sc * 8];
        }

        // mask for this lane's keys: key = ks*16 + quad*4 + r
        int4 mv[4];
        #pragma unroll
        for (int ks = 0; ks < 4; ++ks)
            mv[ks] = *(const int4*)&mp[kt * 64 + ks * 16 + quad * 4];

        // S^T: sacc[ks][qs] -> S^T[key=ks*16+quad*4+r][q=qs*16+col]
        float4v sacc[4][2] = {};
        #pragma unroll
        for (int ks = 0; ks < 4; ++ks) {
            short8 a0 = *(const short8*)(KsB + swz(ks * 16 + col, quad));
            short8 a1 = *(const short8*)(KsB + swz(ks * 16 + col, 4 + quad));
            #pragma unroll
            for (int qs = 0; qs < 2; ++qs) {
                sacc[ks][qs] = __builtin_amdgcn_mfma_f32_16x16x32_bf16(
                    a0, qf[qs][0], sacc[ks][qs], 0, 0, 0);
                sacc[ks][qs] = __builtin_amdgcn_mfma_f32_16x16x32_bf16(
                    a1, qf[qs][1], sacc[ks][qs], 0, 0, 0);
            }
        }

        // softmax (no-max): p = exp2(s' + madd); pack round-half-up to bf16
        #pragma unroll
        for (int ks = 0; ks < 4; ++ks) {
            const int* mi = (const int*)&mv[ks];
            #pragma unroll
            for (int qs = 0; qs < 2; ++qs) {
                ushort4v pw;
                #pragma unroll
                for (int r = 0; r < 4; ++r) {
                    float madd = mi[r] ? MADD_KEEP : -1e30f;   // masked -> exp2 == 0
                    float p = EXPFN(sacc[ks][qs][r] + madd);
                    lsum[qs] += p;
                    union { float f; uint32_t u; } cv; cv.f = p;
                    pw[r] = (unsigned short)((cv.u + 0x8000u) >> 16);
                }
                *(ushort4v*)&Ps[w][qs * 16 + col][ks * 16 + quad * 4] = pw;
            }
        }

        // PV: acc_o[qs][ds] += P (A) * V (B); same-wave Ps write->read
        #pragma unroll
        for (int kk = 0; kk < 2; ++kk) {
            short8 pa0 = *(const short8*)&Ps[w][col][kk * 32 + quad * 8];
            short8 pa1 = *(const short8*)&Ps[w][16 + col][kk * 32 + quad * 8];
            #pragma unroll
            for (int ds = 0; ds < 4; ++ds) {
                short8 vb = *(const short8*)(VsB + swz(ds * 16 + col, kk * 4 + quad));
                acc_o[0][ds] = __builtin_amdgcn_mfma_f32_16x16x32_bf16(
                    pa0, vb, acc_o[0][ds], 0, 0, 0);
                acc_o[1][ds] = __builtin_amdgcn_mfma_f32_16x16x32_bf16(
                    pa1, vb, acc_o[1][ds], 0, 0, 0);
            }
        }
    }

    // l reduction: lane's partial covers its quad's keys; all lanes end with
    // the full l for q = qs*16+col
    #pragma unroll
    for (int qs = 0; qs < 2; ++qs) {
        lsum[qs] += __shfl_xor(lsum[qs], 16);
        lsum[qs] += __shfl_xor(lsum[qs], 32);
    }

    float* Opart = (s == 0) ? O0 : O1;
    #pragma unroll
    for (int qs = 0; qs < 2; ++qs)
        #pragma unroll
        for (int r = 0; r < 4; ++r) {
            int m = q0 + w * 32 + qs * 16 + quad * 4 + r;
            float* og = Opart + ((size_t)bh * Mc + m) * DHc;
            #pragma unroll
            for (int ds = 0; ds < 4; ++ds)
                og[ds * 16 + col] = acc_o[qs][ds][r];
        }
    if (quad == 0) {
        #pragma unroll
        for (int qs = 0; qs < 2; ++qs)
            lpart[((size_t)s * Bc * Hc + bh) * Mc + q0 + w * 32 + qs * 16 + col] = lsum[qs];
    }
}

// ---------------------------------------------------------------------------
// Combine: out = (O0 + O1) / (l0 + l1), 0 where l==0.
// grid 4096, block 256, 4 floats/thread.
// ---------------------------------------------------------------------------
__global__ __launch_bounds__(256)
void combine_kernel(float* __restrict__ out, const float* __restrict__ O1,
                    const float* __restrict__ lpart)
{
    size_t i = ((size_t)blockIdx.x * 256 + threadIdx.x) * 4;
    int row = (int)(i >> 6);   // bh*Mc + m
    float sl = lpart[row] + lpart[(size_t)Bc * Hc * Mc + row];
    float inv = (sl > 0.0f) ? 1.0f / sl : 0.0f;
    float4 a = *(const float4*)&out[i];
    const float4 bb = *(const float4*)&O1[i];
    a.x = (a.x + bb.x) * inv;
    a.y = (a.y + bb.y) * inv;
    a.z = (a.z + bb.z) * inv;
    a.w = (a.w + bb.w) * inv;
    *(float4*)&out[i] = a;
}

extern "C" void kernel_launch(void* const* d_in, const int* in_sizes, int n_in,
                              void* d_out, int out_size, void* d_ws, size_t ws_size,
                              hipStream_t stream) {
    const float* Pq = (const float*)d_in[0];
    const float* Pk = (const float*)d_in[1];
    const float* Pv = (const float*)d_in[2];
    const float* Vq = (const float*)d_in[3];
    const float* Vk = (const float*)d_in[4];
    const float* Vv = (const float*)d_in[5];
    const float* bq = (const float*)d_in[6];
    const float* bk = (const float*)d_in[7];
    const float* bv = (const float*)d_in[8];
    const int*   am = (const int*)d_in[9];
    const int*   pid = (const int*)d_in[10];
    float* out = (float*)d_out;

    // workspace: Qb 8MB | Kb 8MB | Vta 8MB | O1 16.8MB | lpart 512KB = ~41.8MB
    const size_t n_el = (size_t)Bc * Hc * Mc * DHc;            // 4M elements
    unsigned short* Qb  = (unsigned short*)d_ws;
    unsigned short* Kb  = Qb + n_el;
    unsigned short* Vta = Kb + n_el;
    float* O1    = (float*)(Vta + n_el);
    float* lpart = O1 + n_el;

    dim3 blk(256);
    proj_kernel<<<dim3(Mc / 128, Dc / 128, 6), blk, 0, stream>>>(
        Pq, Pk, Pv, Vq, Vk, Vv, bq, bk, bv, pid, Qb, Kb, Vta);

    attn_kernel<<<dim3(Mc / 128, Bc * Hc, NSPLIT), blk, 0, stream>>>(
        Qb, Kb, Vta, am, out, O1, lpart);

    combine_kernel<<<dim3((unsigned)(n_el / 1024)), blk, 0, stream>>>(out, O1, lpart);
}

// Round 5
// 175.469 us; speedup vs baseline: 1.0272x; 1.0272x over previous
//
#include <hip/hip_runtime.h>
#include <cstdint>
#include <cstddef>

// Problem constants (match reference)
#define Bc 2
#define Mc 2048
#define Rc 256
#define Hc 16
#define DHc 64
#define Dc (Hc * DHc)
#define NKT2 16            // key tiles of 64 per split (1024 keys/split)

typedef __attribute__((ext_vector_type(8))) short short8;     // 8 bf16 (4 VGPRs)
typedef __attribute__((ext_vector_type(4))) float float4v;    // MFMA C/D frag
typedef __attribute__((ext_vector_type(4))) unsigned short ushort4v;
typedef __attribute__((ext_vector_type(8))) unsigned short ushort8v;
typedef __attribute__((ext_vector_type(4))) unsigned int uint4v;

// exp path: native exp2 (v_exp_f32); 0.125*log2(e) folded into Q at proj
#if __has_builtin(__builtin_amdgcn_exp2f)
#define EXPFN(x) __builtin_amdgcn_exp2f(x)
#define QSCALE 0.18033688f       // 0.125 * log2(e)
#define MADD_KEEP (-28.8539008f) // -20 * log2(e)
#else
#define EXPFN(x) __expf(x)
#define QSCALE 0.125f
#define MADD_KEEP (-20.0f)
#endif

// round-to-nearest-even f32 -> bf16
__device__ inline unsigned short f2bf(float f) {
    union { float f; uint32_t u; } v;
    v.f = f;
    uint32_t r = v.u + 0x7fffu + ((v.u >> 16) & 1u);
    return (unsigned short)(r >> 16);
}

// XOR-swizzled byte offset for [row][8 x 16B-chunk] LDS tiles (row = 128 B).
__device__ inline int swz(int row, int chunk) {
    return row * 128 + ((chunk ^ (row & 7)) << 4);
}

// ---------------------------------------------------------------------------
// Prep: transpose+convert Vq/Vk/Vv (fp32 [R][D]) -> bf16 [mat][d][k].
// grid (D/256=4, R/8=32, 3), block 256. Coalesced fp32 reads. (verified R2/R3)
// ---------------------------------------------------------------------------
__global__ __launch_bounds__(256)
void transpose_v(const float* __restrict__ V0, const float* __restrict__ V1,
                 const float* __restrict__ V2, unsigned short* __restrict__ Vt)
{
    const int mat = blockIdx.z;
    const float* src = mat == 0 ? V0 : (mat == 1 ? V1 : V2);
    const int d  = blockIdx.x * 256 + threadIdx.x;
    const int kg = blockIdx.y;                       // group of 8 k values
    short8 v;
    #pragma unroll
    for (int j = 0; j < 8; ++j)
        v[j] = (short)f2bf(src[(size_t)(kg * 8 + j) * Dc + d]);
    *(short8*)&Vt[((size_t)mat * Dc + d) * Rc + kg * 8] = v;
}

// ---------------------------------------------------------------------------
// Proj: all three x = P@V + b (+RoPE / +transpose) in one kernel.
// grid (M/128=16, D/128=8, 3 mats * B=6) = 768 blocks, block 256 (4 waves).
// A: fp32 inline-convert to bf16 (vector LDS writes — verified R4).
// B: bf16 b128 copies from pre-transposed Vtp (verified R3; R4's scalar
//    transpose scatter was the proj disaster — removed).
// Wave w owns quadrant (mh=w&1 rows, dh2=w>>1 cols) = 4x4 MFMA tiles.
// mat 0 (Q): RoPE + QSCALE -> [bh][m][dh]; mat 1 (K): RoPE -> same;
// mat 2 (V): transposed [bh][dh][m].
// ---------------------------------------------------------------------------
__global__ __launch_bounds__(256)
void proj_kernel(const float* __restrict__ Pq, const float* __restrict__ Pk,
                 const float* __restrict__ Pv,
                 const unsigned short* __restrict__ Vtp,  // [3][D][R] bf16
                 const float* __restrict__ bq, const float* __restrict__ bk,
                 const float* __restrict__ bv,
                 const int* __restrict__ pos_ids,
                 unsigned short* __restrict__ Qb, unsigned short* __restrict__ Kb,
                 unsigned short* __restrict__ Vta)
{
    __shared__ __align__(16) unsigned char AtB[128 * 128];  // A[m][64k] bf16 swz
    __shared__ __align__(16) unsigned char BtB[128 * 128];  // B[d][64k] bf16 swz

    const int tid = threadIdx.x;
    const int z = blockIdx.z, mat = z >> 1, b = z & 1;
    const int m0 = blockIdx.x * 128, d0 = blockIdx.y * 128;
    const int w = tid >> 6, lane = tid & 63, col = lane & 15, quad = lane >> 4;
    const int mh = w & 1, dh2 = w >> 1;

    const float* P = mat == 0 ? Pq : (mat == 1 ? Pk : Pv);
    const float* Pg = P + ((size_t)b * Mc + m0) * Rc;
    const unsigned short* Vg = Vtp + (size_t)mat * Dc * Rc + (size_t)d0 * Rc;

    // A staging: thread covers row tid>>1, 32 consecutive floats
    const int arow = tid >> 1, ac0 = (tid & 1) * 4;
    // B staging: thread covers d-row tid>>1, 4 16B chunks
    const int brow = tid >> 1, bc0 = (tid & 1) * 4;

    float4v acc[4][4] = {};   // [mt][dt]

    for (int kc = 0; kc < 4; ++kc) {
        float4 af[8];
        uint4v br[4];
        #pragma unroll
        for (int i = 0; i < 8; ++i)
            af[i] = *(const float4*)&Pg[(size_t)arow * Rc + kc * 64 + (tid & 1) * 32 + i * 4];
        #pragma unroll
        for (int i = 0; i < 4; ++i)
            br[i] = *(const uint4v*)&Vg[(size_t)brow * Rc + kc * 64 + (bc0 + i) * 8];
        ushort8v ua[4];
        #pragma unroll
        for (int i = 0; i < 4; ++i) {
            float4 f0 = af[2 * i], f1 = af[2 * i + 1];
            ushort8v u = { f2bf(f0.x), f2bf(f0.y), f2bf(f0.z), f2bf(f0.w),
                           f2bf(f1.x), f2bf(f1.y), f2bf(f1.z), f2bf(f1.w) };
            ua[i] = u;
        }
        __syncthreads();   // previous chunk's readers done
        #pragma unroll
        for (int i = 0; i < 4; ++i) {
            *(ushort8v*)(AtB + swz(arow, ac0 + i)) = ua[i];
            *(uint4v*)(BtB + swz(brow, bc0 + i)) = br[i];
        }
        __syncthreads();

        #pragma unroll
        for (int kk = 0; kk < 2; ++kk) {
            short8 afr[4], bfr[4];
            #pragma unroll
            for (int mt = 0; mt < 4; ++mt)
                afr[mt] = *(const short8*)(AtB + swz(mh * 64 + mt * 16 + col, kk * 4 + quad));
            #pragma unroll
            for (int dt = 0; dt < 4; ++dt)
                bfr[dt] = *(const short8*)(BtB + swz(dh2 * 64 + dt * 16 + col, kk * 4 + quad));
            #pragma unroll
            for (int mt = 0; mt < 4; ++mt)
                #pragma unroll
                for (int dt = 0; dt < 4; ++dt)
                    acc[mt][dt] = __builtin_amdgcn_mfma_f32_16x16x32_bf16(
                        afr[mt], bfr[dt], acc[mt][dt], 0, 0, 0);
        }
    }

    const int head = (d0 + dh2 * 64) >> 6;
    const int bh = b * Hc + head;

    if (mat < 2) {
        const float* bias = mat == 0 ? bq : bk;
        unsigned short* outp = mat == 0 ? Qb : Kb;
        const float oscale = mat == 0 ? QSCALE : 1.0f;
        float b00 = bias[head * 64 + col],      b01 = bias[head * 64 + 16 + col];
        float b10 = bias[head * 64 + 32 + col], b11 = bias[head * 64 + 48 + col];
        float if0 = __expf(-0.28782314f * (float)col);          // 10000^(-j/32)
        float if1 = __expf(-0.28782314f * (float)(col + 16));
        #pragma unroll
        for (int mt = 0; mt < 4; ++mt)
            #pragma unroll
            for (int r = 0; r < 4; ++r) {
                int m = m0 + mh * 64 + mt * 16 + quad * 4 + r;
                float pos = (float)pos_ids[b * Mc + m];
                float a0 = pos * if0, a1 = pos * if1;
                float cs0 = __cosf(a0), sn0 = __sinf(a0);
                float cs1 = __cosf(a1), sn1 = __sinf(a1);
                float x00 = acc[mt][0][r] + b00, x10 = acc[mt][2][r] + b10;
                float x01 = acc[mt][1][r] + b01, x11 = acc[mt][3][r] + b11;
                unsigned short* og = outp + ((size_t)bh * Mc + m) * DHc;
                og[col]      = f2bf((x00 * cs0 - x10 * sn0) * oscale);
                og[32 + col] = f2bf((x00 * sn0 + x10 * cs0) * oscale);
                og[16 + col] = f2bf((x01 * cs1 - x11 * sn1) * oscale);
                og[48 + col] = f2bf((x01 * sn1 + x11 * cs1) * oscale);
            }
    } else {
        #pragma unroll
        for (int dt = 0; dt < 4; ++dt) {
            int d = d0 + dh2 * 64 + dt * 16 + col;
            float bb = bv[d];
            int dh = d & 63;
            #pragma unroll
            for (int mt = 0; mt < 4; ++mt) {
                ushort4v pv;
                #pragma unroll
                for (int r = 0; r < 4; ++r) pv[r] = f2bf(acc[mt][dt][r] + bb);
                size_t base = ((size_t)bh * DHc + dh) * Mc + m0 + mh * 64 + mt * 16 + quad * 4;
                *(ushort4v*)&Vta[base] = pv;
            }
        }
    }
}

// ---------------------------------------------------------------------------
// Attn: flash attention, 64 q/wave, intra-block split-K.
// grid (M/128=16, B*H=32) = 512 blocks, block 256 (4 waves).
// Waves 0,1 (split 0) cover keys [0,1024); waves 2,3 (split 1) [1024,2048).
// Wave w handles queries q0 + (w&1)*64 .. +63. After the K loop, split-1
// waves push O-partials + l through LDS; split-0 waves combine + store.
// LDS (64 KB): Ks[2] 16K | Vs[2] 16K | Ps[4] 32K (aliased as exchange bufs).
// ---------------------------------------------------------------------------
__global__ __launch_bounds__(256, 2)
void attn_kernel(const unsigned short* __restrict__ Qb,
                 const unsigned short* __restrict__ Kb,
                 const unsigned short* __restrict__ Vt,
                 const int* __restrict__ mask,   // [B][M]
                 float* __restrict__ out)
{
    __shared__ __align__(16) unsigned char smem[65536];

    const int tid = threadIdx.x;
    const int q0 = blockIdx.x * 128;
    const int bh = blockIdx.y;
    const int b  = bh >> 4;
    const int w = tid >> 6, lane = tid & 63, col = lane & 15, quad = lane >> 4;
    const int s = w >> 1, qh = w & 1;

    unsigned char* KsB = smem + s * 8192;            // [key 64][dh 64] swz
    unsigned char* VsB = smem + 16384 + s * 8192;    // [dh 64][key 64] swz
    unsigned char* PsB = smem + 32768 + w * 8192;    // per-wave P [q 64][key 64] swz

    // Q frags (B-operand), loop-invariant: q = q0 + qh*64 + qg*16 + col
    short8 qf[4][2];
    #pragma unroll
    for (int qg = 0; qg < 4; ++qg) {
        const unsigned short* Qg =
            Qb + ((size_t)bh * Mc + q0 + qh * 64 + qg * 16 + col) * DHc + quad * 8;
        qf[qg][0] = *(const short8*)Qg;
        qf[qg][1] = *(const short8*)(Qg + 32);
    }

    // staging: 128 threads per split cover 64 rows x 8 chunks (4 per thread)
    const int ts = tid & 127;
    const int srow = ts >> 1, sc0 = (ts & 1) * 4;
    const unsigned short* Kg = Kb + ((size_t)bh * Mc + s * (Mc / 2)) * DHc;
    const unsigned short* Vg = Vt + (size_t)bh * DHc * Mc + s * (Mc / 2);
    const int* mp = mask + b * Mc + s * (Mc / 2);

    uint4v kr[4], vr[4];
    #pragma unroll
    for (int i = 0; i < 4; ++i) {
        kr[i] = *(const uint4v*)&Kg[(size_t)srow * DHc + (sc0 + i) * 8];
        vr[i] = *(const uint4v*)&Vg[(size_t)srow * Mc + (sc0 + i) * 8];
    }

    float lsum[4] = {};
    float4v acc_o[4][4] = {};    // [qg][dh]

    for (int kt = 0; kt < NKT2; ++kt) {
        __syncthreads();
        #pragma unroll
        for (int i = 0; i < 4; ++i) {
            *(uint4v*)(KsB + swz(srow, sc0 + i)) = kr[i];
            *(uint4v*)(VsB + swz(srow, sc0 + i)) = vr[i];
        }
        __syncthreads();

        if (kt + 1 < NKT2) {   // prefetch next tile
            const unsigned short* Kn = Kg + (size_t)(kt + 1) * 64 * DHc;
            #pragma unroll
            for (int i = 0; i < 4; ++i) {
                kr[i] = *(const uint4v*)&Kn[(size_t)srow * DHc + (sc0 + i) * 8];
                vr[i] = *(const uint4v*)&Vg[(size_t)srow * Mc + (kt + 1) * 64 + (sc0 + i) * 8];
            }
        }

        // S^T per 16-key group; exp; pack; Ps write (b64, swizzled)
        #pragma unroll
        for (int ks = 0; ks < 4; ++ks) {
            int4 mv = *(const int4*)&mp[kt * 64 + ks * 16 + quad * 4];
            const int* mi = (const int*)&mv;
            float md[4];
            #pragma unroll
            for (int r = 0; r < 4; ++r) md[r] = mi[r] ? MADD_KEEP : -1e30f;
            short8 a0 = *(const short8*)(KsB + swz(ks * 16 + col, quad));
            short8 a1 = *(const short8*)(KsB + swz(ks * 16 + col, 4 + quad));
            #pragma unroll
            for (int qg = 0; qg < 4; ++qg) {
                float4v sacc = {};
                sacc = __builtin_amdgcn_mfma_f32_16x16x32_bf16(a0, qf[qg][0], sacc, 0, 0, 0);
                sacc = __builtin_amdgcn_mfma_f32_16x16x32_bf16(a1, qf[qg][1], sacc, 0, 0, 0);
                ushort4v pw;
                #pragma unroll
                for (int r = 0; r < 4; ++r) {
                    float p = EXPFN(sacc[r] + md[r]);
                    lsum[qg] += p;
                    union { float f; uint32_t u; } cv; cv.f = p;
                    pw[r] = (unsigned short)((cv.u + 0x8000u) >> 16);
                }
                int qrow = qg * 16 + col;
                *(ushort4v*)(PsB + qrow * 128 +
                             (((ks * 2 + (quad >> 1)) ^ (qrow & 7)) << 4) +
                             (quad & 1) * 8) = pw;
            }
        }

        // PV: acc_o[qg][dh] += P (A) * V (B); same-wave Ps write->read
        #pragma unroll
        for (int kk = 0; kk < 2; ++kk) {
            short8 pa[4];
            #pragma unroll
            for (int qg = 0; qg < 4; ++qg)
                pa[qg] = *(const short8*)(PsB + swz(qg * 16 + col, kk * 4 + quad));
            #pragma unroll
            for (int dh = 0; dh < 4; ++dh) {
                short8 vb = *(const short8*)(VsB + swz(dh * 16 + col, kk * 4 + quad));
                #pragma unroll
                for (int qg = 0; qg < 4; ++qg)
                    acc_o[qg][dh] = __builtin_amdgcn_mfma_f32_16x16x32_bf16(
                        pa[qg], vb, acc_o[qg][dh], 0, 0, 0);
            }
        }
    }

    // l reduction across quads: all lanes end with full split-l for q=qg*16+col
    #pragma unroll
    for (int qg = 0; qg < 4; ++qg) {
        lsum[qg] += __shfl_xor(lsum[qg], 16);
        lsum[qg] += __shfl_xor(lsum[qg], 32);
    }

    // intra-block split combine through LDS
    __syncthreads();
    float* Of = (float*)(smem + 32768 + qh * 16384);   // [q 64][dh 64] fp32
    float* Lf = (float*)smem;                          // [qh 2][q 64]
    if (s == 1) {
        #pragma unroll
        for (int qg = 0; qg < 4; ++qg)
            #pragma unroll
            for (int dh = 0; dh < 4; ++dh)
                #pragma unroll
                for (int r = 0; r < 4; ++r)
                    Of[(qg * 16 + quad * 4 + r) * 64 + dh * 16 + col] = acc_o[qg][dh][r];
        if (quad == 0) {
            #pragma unroll
            for (int qg = 0; qg < 4; ++qg)
                Lf[qh * 64 + qg * 16 + col] = lsum[qg];
        }
    }
    __syncthreads();
    if (s == 0) {
        #pragma unroll
        for (int qg = 0; qg < 4; ++qg)
            #pragma unroll
            for (int r = 0; r < 4; ++r) {
                float l0 = __shfl(lsum[qg], quad * 4 + r);   // l for q row quad*4+r
                float l1 = Lf[qh * 64 + qg * 16 + quad * 4 + r];
                float lt = l0 + l1;
                float inv = (lt > 0.0f) ? 1.0f / lt : 0.0f;
                int m = q0 + qh * 64 + qg * 16 + quad * 4 + r;
                float* og = out + ((size_t)bh * Mc + m) * DHc;
                #pragma unroll
                for (int dh = 0; dh < 4; ++dh)
                    og[dh * 16 + col] =
                        (acc_o[qg][dh][r] + Of[(qg * 16 + quad * 4 + r) * 64 + dh * 16 + col]) * inv;
            }
    }
}

extern "C" void kernel_launch(void* const* d_in, const int* in_sizes, int n_in,
                              void* d_out, int out_size, void* d_ws, size_t ws_size,
                              hipStream_t stream) {
    const float* Pq = (const float*)d_in[0];
    const float* Pk = (const float*)d_in[1];
    const float* Pv = (const float*)d_in[2];
    const float* Vq = (const float*)d_in[3];
    const float* Vk = (const float*)d_in[4];
    const float* Vv = (const float*)d_in[5];
    const float* bq = (const float*)d_in[6];
    const float* bk = (const float*)d_in[7];
    const float* bv = (const float*)d_in[8];
    const int*   am = (const int*)d_in[9];
    const int*   pid = (const int*)d_in[10];
    float* out = (float*)d_out;

    // workspace: Qb 8MB | Kb 8MB | Vta 8MB | Vtp 1.5MB
    const size_t n_el = (size_t)Bc * Hc * Mc * DHc;            // 4M elements
    unsigned short* Qb  = (unsigned short*)d_ws;
    unsigned short* Kb  = Qb + n_el;
    unsigned short* Vta = Kb + n_el;
    unsigned short* Vtp = Vta + n_el;                          // [3][D][R] bf16

    dim3 blk(256);
    transpose_v<<<dim3(Dc / 256, Rc / 8, 3), blk, 0, stream>>>(Vq, Vk, Vv, Vtp);

    proj_kernel<<<dim3(Mc / 128, Dc / 128, 6), blk, 0, stream>>>(
        Pq, Pk, Pv, Vtp, bq, bk, bv, pid, Qb, Kb, Vta);

    attn_kernel<<<dim3(Mc / 128, Bc * Hc), blk, 0, stream>>>(Qb, Kb, Vta, am, out);
}

// Round 6
// 174.614 us; speedup vs baseline: 1.0322x; 1.0049x over previous
//
#include <hip/hip_runtime.h>
#include <cstdint>
#include <cstddef>

// Problem constants (match reference)
#define Bc 2
#define Mc 2048
#define Rc 256
#define Hc 16
#define DHc 64
#define Dc (Hc * DHc)
#define NKT2 16            // key tiles of 64 per split (1024 keys/split)

typedef __attribute__((ext_vector_type(8))) short short8;     // 8 bf16 (4 VGPRs)
typedef __attribute__((ext_vector_type(4))) float float4v;    // MFMA C/D frag
typedef __attribute__((ext_vector_type(4))) unsigned short ushort4v;
typedef __attribute__((ext_vector_type(8))) unsigned short ushort8v;
typedef __attribute__((ext_vector_type(4))) unsigned int uint4v;

// exp path: native exp2 (v_exp_f32); 0.125*log2(e) folded into Q at proj
#if __has_builtin(__builtin_amdgcn_exp2f)
#define EXPFN(x) __builtin_amdgcn_exp2f(x)
#define QSCALE 0.18033688f       // 0.125 * log2(e)
#define MADD_KEEP (-28.8539008f) // -20 * log2(e)
#else
#define EXPFN(x) __expf(x)
#define QSCALE 0.125f
#define MADD_KEEP (-20.0f)
#endif

// round-to-nearest-even f32 -> bf16
__device__ inline unsigned short f2bf(float f) {
    union { float f; uint32_t u; } v;
    v.f = f;
    uint32_t r = v.u + 0x7fffu + ((v.u >> 16) & 1u);
    return (unsigned short)(r >> 16);
}

// XOR-swizzled byte offset for [row][8 x 16B-chunk] LDS tiles (row = 128 B).
__device__ inline int swz(int row, int chunk) {
    return row * 128 + ((chunk ^ (row & 7)) << 4);
}

// ---------------------------------------------------------------------------
// Prep: transpose+convert Vq/Vk/Vv (fp32 [R][D]) -> bf16 [mat][d][k].
// grid (D/256=4, R/8=32, 3), block 256. Coalesced fp32 reads. (verified R2/R3)
// ---------------------------------------------------------------------------
__global__ __launch_bounds__(256)
void transpose_v(const float* __restrict__ V0, const float* __restrict__ V1,
                 const float* __restrict__ V2, unsigned short* __restrict__ Vt)
{
    const int mat = blockIdx.z;
    const float* src = mat == 0 ? V0 : (mat == 1 ? V1 : V2);
    const int d  = blockIdx.x * 256 + threadIdx.x;
    const int kg = blockIdx.y;                       // group of 8 k values
    short8 v;
    #pragma unroll
    for (int j = 0; j < 8; ++j)
        v[j] = (short)f2bf(src[(size_t)(kg * 8 + j) * Dc + d]);
    *(short8*)&Vt[((size_t)mat * Dc + d) * Rc + kg * 8] = v;
}

// ---------------------------------------------------------------------------
// Proj: all three x = P@V + b (+RoPE / +transpose) in one kernel.
// grid (M/128=16, D/128=8, 3 mats * B=6) = 768 blocks, block 256 (4 waves).
// (UNCHANGED from round 5 — held constant for attribution.)
// ---------------------------------------------------------------------------
__global__ __launch_bounds__(256)
void proj_kernel(const float* __restrict__ Pq, const float* __restrict__ Pk,
                 const float* __restrict__ Pv,
                 const unsigned short* __restrict__ Vtp,  // [3][D][R] bf16
                 const float* __restrict__ bq, const float* __restrict__ bk,
                 const float* __restrict__ bv,
                 const int* __restrict__ pos_ids,
                 unsigned short* __restrict__ Qb, unsigned short* __restrict__ Kb,
                 unsigned short* __restrict__ Vta)
{
    __shared__ __align__(16) unsigned char AtB[128 * 128];  // A[m][64k] bf16 swz
    __shared__ __align__(16) unsigned char BtB[128 * 128];  // B[d][64k] bf16 swz

    const int tid = threadIdx.x;
    const int z = blockIdx.z, mat = z >> 1, b = z & 1;
    const int m0 = blockIdx.x * 128, d0 = blockIdx.y * 128;
    const int w = tid >> 6, lane = tid & 63, col = lane & 15, quad = lane >> 4;
    const int mh = w & 1, dh2 = w >> 1;

    const float* P = mat == 0 ? Pq : (mat == 1 ? Pk : Pv);
    const float* Pg = P + ((size_t)b * Mc + m0) * Rc;
    const unsigned short* Vg = Vtp + (size_t)mat * Dc * Rc + (size_t)d0 * Rc;

    const int arow = tid >> 1, ac0 = (tid & 1) * 4;
    const int brow = tid >> 1, bc0 = (tid & 1) * 4;

    float4v acc[4][4] = {};   // [mt][dt]

    for (int kc = 0; kc < 4; ++kc) {
        float4 af[8];
        uint4v br[4];
        #pragma unroll
        for (int i = 0; i < 8; ++i)
            af[i] = *(const float4*)&Pg[(size_t)arow * Rc + kc * 64 + (tid & 1) * 32 + i * 4];
        #pragma unroll
        for (int i = 0; i < 4; ++i)
            br[i] = *(const uint4v*)&Vg[(size_t)brow * Rc + kc * 64 + (bc0 + i) * 8];
        ushort8v ua[4];
        #pragma unroll
        for (int i = 0; i < 4; ++i) {
            float4 f0 = af[2 * i], f1 = af[2 * i + 1];
            ushort8v u = { f2bf(f0.x), f2bf(f0.y), f2bf(f0.z), f2bf(f0.w),
                           f2bf(f1.x), f2bf(f1.y), f2bf(f1.z), f2bf(f1.w) };
            ua[i] = u;
        }
        __syncthreads();   // previous chunk's readers done
        #pragma unroll
        for (int i = 0; i < 4; ++i) {
            *(ushort8v*)(AtB + swz(arow, ac0 + i)) = ua[i];
            *(uint4v*)(BtB + swz(brow, bc0 + i)) = br[i];
        }
        __syncthreads();

        #pragma unroll
        for (int kk = 0; kk < 2; ++kk) {
            short8 afr[4], bfr[4];
            #pragma unroll
            for (int mt = 0; mt < 4; ++mt)
                afr[mt] = *(const short8*)(AtB + swz(mh * 64 + mt * 16 + col, kk * 4 + quad));
            #pragma unroll
            for (int dt = 0; dt < 4; ++dt)
                bfr[dt] = *(const short8*)(BtB + swz(dh2 * 64 + dt * 16 + col, kk * 4 + quad));
            #pragma unroll
            for (int mt = 0; mt < 4; ++mt)
                #pragma unroll
                for (int dt = 0; dt < 4; ++dt)
                    acc[mt][dt] = __builtin_amdgcn_mfma_f32_16x16x32_bf16(
                        afr[mt], bfr[dt], acc[mt][dt], 0, 0, 0);
        }
    }

    const int head = (d0 + dh2 * 64) >> 6;
    const int bh = b * Hc + head;

    if (mat < 2) {
        const float* bias = mat == 0 ? bq : bk;
        unsigned short* outp = mat == 0 ? Qb : Kb;
        const float oscale = mat == 0 ? QSCALE : 1.0f;
        float b00 = bias[head * 64 + col],      b01 = bias[head * 64 + 16 + col];
        float b10 = bias[head * 64 + 32 + col], b11 = bias[head * 64 + 48 + col];
        float if0 = __expf(-0.28782314f * (float)col);          // 10000^(-j/32)
        float if1 = __expf(-0.28782314f * (float)(col + 16));
        #pragma unroll
        for (int mt = 0; mt < 4; ++mt)
            #pragma unroll
            for (int r = 0; r < 4; ++r) {
                int m = m0 + mh * 64 + mt * 16 + quad * 4 + r;
                float pos = (float)pos_ids[b * Mc + m];
                float a0 = pos * if0, a1 = pos * if1;
                float cs0 = __cosf(a0), sn0 = __sinf(a0);
                float cs1 = __cosf(a1), sn1 = __sinf(a1);
                float x00 = acc[mt][0][r] + b00, x10 = acc[mt][2][r] + b10;
                float x01 = acc[mt][1][r] + b01, x11 = acc[mt][3][r] + b11;
                unsigned short* og = outp + ((size_t)bh * Mc + m) * DHc;
                og[col]      = f2bf((x00 * cs0 - x10 * sn0) * oscale);
                og[32 + col] = f2bf((x00 * sn0 + x10 * cs0) * oscale);
                og[16 + col] = f2bf((x01 * cs1 - x11 * sn1) * oscale);
                og[48 + col] = f2bf((x01 * sn1 + x11 * cs1) * oscale);
            }
    } else {
        #pragma unroll
        for (int dt = 0; dt < 4; ++dt) {
            int d = d0 + dh2 * 64 + dt * 16 + col;
            float bb = bv[d];
            int dh = d & 63;
            #pragma unroll
            for (int mt = 0; mt < 4; ++mt) {
                ushort4v pv;
                #pragma unroll
                for (int r = 0; r < 4; ++r) pv[r] = f2bf(acc[mt][dt][r] + bb);
                size_t base = ((size_t)bh * DHc + dh) * Mc + m0 + mh * 64 + mt * 16 + quad * 4;
                *(ushort4v*)&Vta[base] = pv;
            }
        }
    }
}

// ---------------------------------------------------------------------------
// Attn v6: 64q-block, 4 waves = 2 q-halves (qh) x 2 key-splits (s).
// grid (M/64=32, B*H=32) = 1024 blocks -> 4 blocks/CU, 16 waves/CU.
// LDS 32 KB: Ks[2] 8K + Vs[2] 8K. P is written INTO the Ks region after the
// 3rd barrier (K-tile dead once all S-frag reads are done) -> no Ps buffer.
// 3 barriers/iter: [b1 restage-safe][stage][b2][S-MFMA][b3][exp+Ps->Ks][PV].
// Split combine through freed LDS at the end (no combine kernel).
// ---------------------------------------------------------------------------
__global__ __launch_bounds__(256, 4)
void attn_kernel(const unsigned short* __restrict__ Qb,
                 const unsigned short* __restrict__ Kb,
                 const unsigned short* __restrict__ Vt,
                 const int* __restrict__ mask,   // [B][M]
                 float* __restrict__ out)
{
    __shared__ __align__(16) unsigned char smem[32768];

    const int tid = threadIdx.x;
    const int q0 = blockIdx.x * 64;
    const int bh = blockIdx.y;
    const int b  = bh >> 4;
    const int w = tid >> 6, lane = tid & 63, col = lane & 15, quad = lane >> 4;
    const int qh = w & 1, s = w >> 1;

    unsigned char* KsB = smem + s * 8192;            // [key 64][dh 64] swz
    unsigned char* VsB = smem + 16384 + s * 8192;    // [dh 64][key 64] swz
    unsigned char* PsB = KsB + qh * 4096;            // P [q 32][key 64] swz (aliased)

    // Q frags (B-operand), loop-invariant: q = q0 + qh*32 + qg*16 + col
    short8 qf[2][2];
    #pragma unroll
    for (int qg = 0; qg < 2; ++qg) {
        const unsigned short* Qg =
            Qb + ((size_t)bh * Mc + q0 + qh * 32 + qg * 16 + col) * DHc + quad * 8;
        qf[qg][0] = *(const short8*)Qg;
        qf[qg][1] = *(const short8*)(Qg + 32);
    }

    // staging: 128 threads (both qh-waves of split s) cover 64 rows x 8 chunks
    const int ts = tid & 127;
    const int srow = ts >> 1, sc0 = (ts & 1) * 4;
    const unsigned short* Kg = Kb + ((size_t)bh * Mc + s * (Mc / 2)) * DHc;
    const unsigned short* Vg = Vt + (size_t)bh * DHc * Mc + s * (Mc / 2);
    const int* mp = mask + b * Mc + s * (Mc / 2);

    uint4v kr[4], vr[4];
    #pragma unroll
    for (int i = 0; i < 4; ++i) {
        kr[i] = *(const uint4v*)&Kg[(size_t)srow * DHc + (sc0 + i) * 8];
        vr[i] = *(const uint4v*)&Vg[(size_t)srow * Mc + (sc0 + i) * 8];
    }

    float lsum[2] = {};
    float4v acc_o[2][4] = {};    // [qg][dh]

    for (int kt = 0; kt < NKT2; ++kt) {
        __syncthreads();   // b1: prior PV (Ps-in-Ks) + Vs reads complete
        #pragma unroll
        for (int i = 0; i < 4; ++i) {
            *(uint4v*)(KsB + swz(srow, sc0 + i)) = kr[i];
            *(uint4v*)(VsB + swz(srow, sc0 + i)) = vr[i];
        }
        __syncthreads();   // b2: tiles visible

        // ---- S phase: all K-frag reads happen here ----
        float4v sacc[4][2] = {};
        #pragma unroll
        for (int ks = 0; ks < 4; ++ks) {
            short8 a0 = *(const short8*)(KsB + swz(ks * 16 + col, quad));      // dh 0..31
            short8 a1 = *(const short8*)(KsB + swz(ks * 16 + col, 4 + quad));  // dh 32..63
            #pragma unroll
            for (int qg = 0; qg < 2; ++qg) {
                sacc[ks][qg] = __builtin_amdgcn_mfma_f32_16x16x32_bf16(
                    a0, qf[qg][0], sacc[ks][qg], 0, 0, 0);
                sacc[ks][qg] = __builtin_amdgcn_mfma_f32_16x16x32_bf16(
                    a1, qf[qg][1], sacc[ks][qg], 0, 0, 0);
            }
        }
        __syncthreads();   // b3: every wave done reading Ks -> reuse as Ps

        // ---- exp + P write into Ks region ----
        #pragma unroll
        for (int ks = 0; ks < 4; ++ks) {
            int4 mv = *(const int4*)&mp[kt * 64 + ks * 16 + quad * 4];
            const int* mi = (const int*)&mv;
            #pragma unroll
            for (int qg = 0; qg < 2; ++qg) {
                ushort4v pw;
                #pragma unroll
                for (int r = 0; r < 4; ++r) {
                    float madd = mi[r] ? MADD_KEEP : -1e30f;   // masked -> exp2 == 0
                    float p = EXPFN(sacc[ks][qg][r] + madd);
                    lsum[qg] += p;
                    union { float f; uint32_t u; } cv; cv.f = p;
                    pw[r] = (unsigned short)((cv.u + 0x8000u) >> 16);
                }
                int qrow = qg * 16 + col;
                *(ushort4v*)(PsB + qrow * 128 +
                             (((ks * 2 + (quad >> 1)) ^ (qrow & 7)) << 4) +
                             (quad & 1) * 8) = pw;
            }
        }

        // prefetch next tile (deferred: shortens kr/vr live range vs sacc)
        if (kt + 1 < NKT2) {
            const unsigned short* Kn = Kg + (size_t)(kt + 1) * 64 * DHc;
            #pragma unroll
            for (int i = 0; i < 4; ++i) {
                kr[i] = *(const uint4v*)&Kn[(size_t)srow * DHc + (sc0 + i) * 8];
                vr[i] = *(const uint4v*)&Vg[(size_t)srow * Mc + (kt + 1) * 64 + (sc0 + i) * 8];
            }
        }

        // ---- PV: acc_o[qg][dh] += P (A, own Ps) * V (B, shared Vs) ----
        #pragma unroll
        for (int kk = 0; kk < 2; ++kk) {
            short8 pa[2];
            #pragma unroll
            for (int qg = 0; qg < 2; ++qg)
                pa[qg] = *(const short8*)(PsB + swz(qg * 16 + col, kk * 4 + quad));
            #pragma unroll
            for (int dh = 0; dh < 4; ++dh) {
                short8 vb = *(const short8*)(VsB + swz(dh * 16 + col, kk * 4 + quad));
                #pragma unroll
                for (int qg = 0; qg < 2; ++qg)
                    acc_o[qg][dh] = __builtin_amdgcn_mfma_f32_16x16x32_bf16(
                        pa[qg], vb, acc_o[qg][dh], 0, 0, 0);
            }
        }
    }

    // split-local l: reduce over quads -> every lane holds l_s(q = qg*16+col)
    #pragma unroll
    for (int qg = 0; qg < 2; ++qg) {
        lsum[qg] += __shfl_xor(lsum[qg], 16);
        lsum[qg] += __shfl_xor(lsum[qg], 32);
    }

    // intra-block split combine through LDS (all tiles dead now)
    __syncthreads();
    float* Of = (float*)(smem + qh * 8192);            // [q 32][dh 64] fp32
    float* Lf = (float*)(smem + 16384);                // [qh 2][q 32]
    if (s == 1) {
        #pragma unroll
        for (int qg = 0; qg < 2; ++qg)
            #pragma unroll
            for (int dh = 0; dh < 4; ++dh)
                #pragma unroll
                for (int r = 0; r < 4; ++r)
                    Of[(qg * 16 + quad * 4 + r) * 64 + dh * 16 + col] = acc_o[qg][dh][r];
        if (quad == 0) {
            #pragma unroll
            for (int qg = 0; qg < 2; ++qg)
                Lf[qh * 32 + qg * 16 + col] = lsum[qg];
        }
    }
    __syncthreads();
    if (s == 0) {
        #pragma unroll
        for (int qg = 0; qg < 2; ++qg)
            #pragma unroll
            for (int r = 0; r < 4; ++r) {
                float l0 = __shfl(lsum[qg], quad * 4 + r);       // lane col=quad*4+r
                float l1 = Lf[qh * 32 + qg * 16 + quad * 4 + r];
                float lt = l0 + l1;
                float inv = (lt > 0.0f) ? 1.0f / lt : 0.0f;
                int m = q0 + qh * 32 + qg * 16 + quad * 4 + r;
                float* og = out + ((size_t)bh * Mc + m) * DHc;
                #pragma unroll
                for (int dh = 0; dh < 4; ++dh)
                    og[dh * 16 + col] =
                        (acc_o[qg][dh][r] + Of[(qg * 16 + quad * 4 + r) * 64 + dh * 16 + col]) * inv;
            }
    }
}

extern "C" void kernel_launch(void* const* d_in, const int* in_sizes, int n_in,
                              void* d_out, int out_size, void* d_ws, size_t ws_size,
                              hipStream_t stream) {
    const float* Pq = (const float*)d_in[0];
    const float* Pk = (const float*)d_in[1];
    const float* Pv = (const float*)d_in[2];
    const float* Vq = (const float*)d_in[3];
    const float* Vk = (const float*)d_in[4];
    const float* Vv = (const float*)d_in[5];
    const float* bq = (const float*)d_in[6];
    const float* bk = (const float*)d_in[7];
    const float* bv = (const float*)d_in[8];
    const int*   am = (const int*)d_in[9];
    const int*   pid = (const int*)d_in[10];
    float* out = (float*)d_out;

    // workspace: Qb 8MB | Kb 8MB | Vta 8MB | Vtp 1.5MB
    const size_t n_el = (size_t)Bc * Hc * Mc * DHc;            // 4M elements
    unsigned short* Qb  = (unsigned short*)d_ws;
    unsigned short* Kb  = Qb + n_el;
    unsigned short* Vta = Kb + n_el;
    unsigned short* Vtp = Vta + n_el;                          // [3][D][R] bf16

    dim3 blk(256);
    transpose_v<<<dim3(Dc / 256, Rc / 8, 3), blk, 0, stream>>>(Vq, Vk, Vv, Vtp);

    proj_kernel<<<dim3(Mc / 128, Dc / 128, 6), blk, 0, stream>>>(
        Pq, Pk, Pv, Vtp, bq, bk, bv, pid, Qb, Kb, Vta);

    attn_kernel<<<dim3(Mc / 64, Bc * Hc), blk, 0, stream>>>(Qb, Kb, Vta, am, out);
}